// Round 3
// baseline (226.256 us; speedup 1.0000x reference)
//
#include <hip/hip_runtime.h>
#include <math.h>

#define BB 16
#define CC 256
#define HALF 128
#define HW 6400
#define OCH 127   // HALF-1
#define ICH 129   // HALF+1
#define BN_EPS 1e-5f
#define PIX 64    // pixels per block
#define NW 4      // waves per block
#define T1S 68    // t1 row stride in bf16 elems (8B-aligned, bank-spread)

__device__ __forceinline__ unsigned short f2bf(float f) {
    unsigned int u = __float_as_uint(f);
    unsigned int r = (u + 0x7FFFu + ((u >> 16) & 1u)) >> 16;
    return (unsigned short)r;
}
__device__ __forceinline__ float bf2f(unsigned short u) {
    return __uint_as_float((unsigned int)u << 16);
}

// ---------------- kernel 1: per-(b,c) spatial mean (float4) ----------------
__global__ __launch_bounds__(256) void k_means(const float* __restrict__ x1,
                                               float* __restrict__ means) {
    int bc = blockIdx.x;
    const float4* p = (const float4*)(x1 + (size_t)bc * HW);
    float s = 0.f;
    for (int i = threadIdx.x; i < HW / 4; i += 256) {
        float4 v = p[i];
        s += (v.x + v.y) + (v.z + v.w);
    }
    #pragma unroll
    for (int off = 32; off; off >>= 1) s += __shfl_down(s, off, 64);
    __shared__ float red[4];
    int lane = threadIdx.x & 63, w = threadIdx.x >> 6;
    if (lane == 0) red[w] = s;
    __syncthreads();
    if (threadIdx.x == 0) {
        float t = red[0] + red[1] + red[2] + red[3];
        means[bc] = t * (1.0f / HW);
    }
}

// ---------------- kernel 2: ECA conv + sigmoid + top-k selection ----------------
__global__ __launch_bounds__(256) void k_select(const float* __restrict__ means,
                                                const float* __restrict__ eca_w,
                                                int* __restrict__ posidx,
                                                int* __restrict__ negidx) {
    int b = blockIdx.x;
    int c = threadIdx.x;
    __shared__ float m[CC];
    __shared__ float s[CC];
    __shared__ int flag[CC];
    m[c] = means[b * CC + c];
    __syncthreads();
    float y = 0.f;
    #pragma unroll
    for (int k = 0; k < 5; k++) {
        int cc = c + k - 2;
        float mv = (cc >= 0 && cc < CC) ? m[cc] : 0.f;
        y += eca_w[k] * mv;
    }
    float sc = 1.f / (1.f + expf(-y));
    s[c] = sc;
    __syncthreads();
    int rank = 0;
    for (int j = 0; j < CC; j++) {
        float sj = s[j];
        rank += (sj > sc) || (sj == sc && j < c);
    }
    int ispos = (rank < HALF) ? 1 : 0;
    flag[c] = ispos;
    __syncthreads();
    int pre = 0;
    for (int j = 0; j < c; j++) pre += flag[j];
    if (ispos) posidx[b * HALF + pre] = c;
    else       negidx[b * HALF + (c - pre)] = c;
}

// ---------------- kernel 3: transpose conv_w, pad to 128 cols, zero tail ----
__global__ __launch_bounds__(256) void k_wt(const float* __restrict__ cw,
                                            float* __restrict__ WT) {
    for (int idx = threadIdx.x + blockIdx.x * 256; idx < ICH * 128; idx += 256 * gridDim.x) {
        int i = idx / 128, o = idx % 128;
        WT[idx] = (o < OCH) ? cw[o * ICH + i] : 0.f;
    }
}

// ---------------- kernel 4: main fused kernel ----------------
// 256 threads = 4 waves, 64 pixels/block. float4 phases remap tid ->
// (cgrp = tid>>4 in 0..15, q = tid&15 float4-chunk of the 64 pixels).
__global__ __launch_bounds__(256, 6) void k_main(const float* __restrict__ x0,
                                                 const float* __restrict__ x1,
                                                 const float* __restrict__ WT,
                                                 const int* __restrict__ posidx,
                                                 const int* __restrict__ negidx,
                                                 const float* __restrict__ bn_gamma,
                                                 const float* __restrict__ bn_beta,
                                                 const float* __restrict__ bn_mean,
                                                 const float* __restrict__ bn_var,
                                                 float* __restrict__ out) {
    int blk = blockIdx.x;
    int b = blk / (HW / PIX);
    int tile = blk % (HW / PIX);
    int p0 = tile * PIX;
    int tid = threadIdx.x;
    int q = tid & 15;          // float4 chunk
    int cgrp = tid >> 4;       // 0..15 channel subgroup
    int lane = tid & 63;
    int w = tid >> 6;

    __shared__ unsigned short t1u[ICH * T1S];   // tmp1 bf16 (later reused for t2)
    __shared__ float snegA[16 * PIX];

    const float* x1b = x1 + (size_t)b * CC * HW;
    const float* x0b = x0 + (size_t)b * CC * HW;
    float* outb = out + (size_t)b * 2 * CC * HW;
    const int* pidx = posidx + b * HALF;
    const int* nidx = negidx + b * HALF;

    // preload this thread's gather indices
    int cj[8], cn[8];
    #pragma unroll
    for (int s = 0; s < 8; s++) {
        int j = s * 16 + cgrp;
        cj[s] = pidx[j];
        cn[s] = nidx[j];
    }

    // ---- phase A: pos gather + direct + neg gather, all float4 ----
    float4 vs = make_float4(0.f, 0.f, 0.f, 0.f);
    #pragma unroll
    for (int s = 0; s < 8; s++) {
        int j = s * 16 + cgrp;
        const float4* pp = (const float4*)(x1b + (size_t)cj[s] * HW + p0);
        const float4* pd = (const float4*)(x1b + (size_t)j * HW + p0);
        const float4* pn = (const float4*)(x1b + (size_t)cn[s] * HW + p0);
        float4 vp = pp[q];
        float4 vd = pd[q];
        float4 vn = pn[q];
        float4 so = make_float4(vd.x + vp.x, vd.y + vp.y, vd.z + vp.z, vd.w + vp.w);
        ((float4*)(outb + (size_t)(CC + j) * HW + p0))[q] = so;
        ushort4 uv;
        uv.x = f2bf(vp.x); uv.y = f2bf(vp.y); uv.z = f2bf(vp.z); uv.w = f2bf(vp.w);
        *(ushort4*)&t1u[j * T1S + q * 4] = uv;
        vs.x += vn.x; vs.y += vn.y; vs.z += vn.z; vs.w += vn.w;
    }
    *(float4*)&snegA[cgrp * PIX + q * 4] = vs;
    __syncthreads();

    // ---- neg mean (wave 0), store t1 row 128 + out row 384 ----
    if (tid < 64) {
        float m = 0.f;
        #pragma unroll
        for (int k = 0; k < 16; k++) m += snegA[k * PIX + tid];
        m *= (1.0f / HALF);
        t1u[HALF * T1S + tid] = f2bf(m);
        outb[(size_t)(CC + HALF) * HW + p0 + tid] = x1b[(size_t)HALF * HW + p0 + tid] + m;
    }
    __syncthreads();

    // ---- phase B: z[32] accumulate over 129 bf16 LDS rows, scalar weights ----
    int sg = __builtin_amdgcn_readfirstlane(w);
    const float* wbase = WT + sg * 32;
    float z[32];
    #pragma unroll
    for (int k = 0; k < 32; k++) z[k] = 0.f;
    for (int i = 0; i < ICH; i++) {
        float v = bf2f(t1u[i * T1S + lane]);
        const float* wc = wbase + i * 128;
        #pragma unroll
        for (int k = 0; k < 32; k++) z[k] += wc[k] * v;
    }

    // ---- BN + leaky in registers, restage t2 as bf16 into t1 buffer ----
    __syncthreads();   // all waves done reading t1
    #pragma unroll
    for (int k = 0; k < 32; k++) {
        int o = sg * 32 + k;
        if (o < OCH) {
            float scale = bn_gamma[o] * rsqrtf(bn_var[o] + BN_EPS);
            float zz = (z[k] - bn_mean[o]) * scale + bn_beta[o];
            float t2 = zz > 0.f ? zz : 0.1f * zz;
            t1u[o * T1S + lane] = f2bf(t2);
        }
    }
    __syncthreads();

    // ---- phase C: final half-2 writes, float4 ----
    #pragma unroll
    for (int s = 0; s < 8; s++) {
        int o = s * 16 + cgrp;
        if (o < OCH) {
            ushort4 uv = *(ushort4*)&t1u[o * T1S + q * 4];
            float4 t2v = make_float4(bf2f(uv.x), bf2f(uv.y), bf2f(uv.z), bf2f(uv.w));
            const float4* px = (const float4*)(x1b + (size_t)(HALF + 1 + o) * HW + p0);
            float4 xv = px[q];
            float4 ov = make_float4(xv.x + t2v.x, xv.y + t2v.y, xv.z + t2v.z, xv.w + t2v.w);
            ((float4*)(outb + (size_t)(CC + HALF + 1 + o) * HW + p0))[q] = ov;
        }
    }

    // ---- phase D: x0 copy, float4 ----
    #pragma unroll 4
    for (int s = 0; s < 16; s++) {
        int c = s * 16 + cgrp;
        float4 v = ((const float4*)(x0b + (size_t)c * HW + p0))[q];
        ((float4*)(outb + (size_t)c * HW + p0))[q] = v;
    }
}

extern "C" void kernel_launch(void* const* d_in, const int* in_sizes, int n_in,
                              void* d_out, int out_size, void* d_ws, size_t ws_size,
                              hipStream_t stream) {
    const float* x0      = (const float*)d_in[0];
    const float* x1      = (const float*)d_in[1];
    const float* eca_w   = (const float*)d_in[2];
    const float* conv_w  = (const float*)d_in[3];
    const float* bn_gamma= (const float*)d_in[4];
    const float* bn_beta = (const float*)d_in[5];
    const float* bn_mean = (const float*)d_in[6];
    const float* bn_var  = (const float*)d_in[7];
    float* out = (float*)d_out;

    float* ws    = (float*)d_ws;
    float* means = ws;                       // 4096 f32
    int*   posidx = (int*)(ws + 4096);       // 2048 i32
    int*   negidx = posidx + 2048;           // 2048 i32
    float* WT    = ws + 4096 + 2048 + 2048;  // 129*128 f32

    k_means<<<BB * CC, 256, 0, stream>>>(x1, means);
    k_select<<<BB, 256, 0, stream>>>(means, eca_w, posidx, negidx);
    k_wt<<<65, 256, 0, stream>>>(conv_w, WT);
    k_main<<<BB * (HW / PIX), 256, 0, stream>>>(x0, x1, WT, posidx, negidx,
                                                bn_gamma, bn_beta, bn_mean, bn_var, out);
}

// Round 4
// 150.044 us; speedup vs baseline: 1.5079x; 1.5079x over previous
//
#include <hip/hip_runtime.h>
#include <math.h>

#define BB 16
#define CC 256
#define HALF 128
#define HW 6400
#define OCH 127   // HALF-1
#define ICH 129   // HALF+1
#define BN_EPS 1e-5f
#define PIX 64    // pixels per block
#define NW 4      // waves per block

// ---------------- kernel 1: per-(b,c) spatial mean (float4) ----------------
__global__ __launch_bounds__(256) void k_means(const float* __restrict__ x1,
                                               float* __restrict__ means) {
    int bc = blockIdx.x;
    const float4* p = (const float4*)(x1 + (size_t)bc * HW);
    float s = 0.f;
    for (int i = threadIdx.x; i < HW / 4; i += 256) {
        float4 v = p[i];
        s += (v.x + v.y) + (v.z + v.w);
    }
    #pragma unroll
    for (int off = 32; off; off >>= 1) s += __shfl_down(s, off, 64);
    __shared__ float red[4];
    int lane = threadIdx.x & 63, w = threadIdx.x >> 6;
    if (lane == 0) red[w] = s;
    __syncthreads();
    if (threadIdx.x == 0) {
        float t = red[0] + red[1] + red[2] + red[3];
        means[bc] = t * (1.0f / HW);
    }
}

// ---------------- kernel 2: ECA conv + sigmoid + top-k selection ----------------
__global__ __launch_bounds__(256) void k_select(const float* __restrict__ means,
                                                const float* __restrict__ eca_w,
                                                int* __restrict__ posidx,
                                                int* __restrict__ negidx) {
    int b = blockIdx.x;
    int c = threadIdx.x;
    __shared__ float m[CC];
    __shared__ float s[CC];
    __shared__ int flag[CC];
    m[c] = means[b * CC + c];
    __syncthreads();
    float y = 0.f;
    #pragma unroll
    for (int k = 0; k < 5; k++) {
        int cc = c + k - 2;
        float mv = (cc >= 0 && cc < CC) ? m[cc] : 0.f;
        y += eca_w[k] * mv;
    }
    float sc = 1.f / (1.f + expf(-y));
    s[c] = sc;
    __syncthreads();
    int rank = 0;
    for (int j = 0; j < CC; j++) {
        float sj = s[j];
        rank += (sj > sc) || (sj == sc && j < c);
    }
    int ispos = (rank < HALF) ? 1 : 0;
    flag[c] = ispos;
    __syncthreads();
    int pre = 0;
    for (int j = 0; j < c; j++) pre += flag[j];
    if (ispos) posidx[b * HALF + pre] = c;
    else       negidx[b * HALF + (c - pre)] = c;
}

// ---------------- kernel 3: transpose conv_w, pad to 128 cols, zero tail ----
__global__ __launch_bounds__(256) void k_wt(const float* __restrict__ cw,
                                            float* __restrict__ WT) {
    for (int idx = threadIdx.x + blockIdx.x * 256; idx < ICH * 128; idx += 256 * gridDim.x) {
        int i = idx / 128, o = idx % 128;
        WT[idx] = (o < OCH) ? cw[o * ICH + i] : 0.f;
    }
}

// ---------------- kernel 4: main fused kernel ----------------
// 256 threads = 4 waves, 64 pixels/block. No tmp1 LDS staging: phase B
// re-gathers pos channels from global (L1/L2/LLC-hot, wave-uniform rows).
__global__ __launch_bounds__(256) void k_main(const float* __restrict__ x0,
                                              const float* __restrict__ x1,
                                              const float* __restrict__ WT,
                                              const int* __restrict__ posidx,
                                              const int* __restrict__ negidx,
                                              const float* __restrict__ bn_gamma,
                                              const float* __restrict__ bn_beta,
                                              const float* __restrict__ bn_mean,
                                              const float* __restrict__ bn_var,
                                              float* __restrict__ out) {
    int blk = blockIdx.x;
    int b = blk / (HW / PIX);
    int tile = blk % (HW / PIX);
    int p0 = tile * PIX;
    int tid = threadIdx.x;
    int q = tid & 15;          // float4 chunk
    int cgrp = tid >> 4;       // 0..15 channel subgroup
    int lane = tid & 63;
    int w = tid >> 6;

    __shared__ float snegA[16 * PIX];   // per-cgrp partial neg sums
    __shared__ float mlds[PIX];         // per-pixel neg mean

    const float* x1b = x1 + (size_t)b * CC * HW;
    const float* x0b = x0 + (size_t)b * CC * HW;
    float* outb = out + (size_t)b * 2 * CC * HW;
    const int* pidx = posidx + b * HALF;
    const int* nidx = negidx + b * HALF;

    // preload this thread's gather indices
    int cj[8], cn[8];
    #pragma unroll
    for (int s = 0; s < 8; s++) {
        int j = s * 16 + cgrp;
        cj[s] = pidx[j];
        cn[s] = nidx[j];
    }

    // ---- phase A: pos gather + direct + neg gather, all float4 ----
    float4 vs = make_float4(0.f, 0.f, 0.f, 0.f);
    #pragma unroll
    for (int s = 0; s < 8; s++) {
        int j = s * 16 + cgrp;
        const float4* pp = (const float4*)(x1b + (size_t)cj[s] * HW + p0);
        const float4* pd = (const float4*)(x1b + (size_t)j * HW + p0);
        const float4* pn = (const float4*)(x1b + (size_t)cn[s] * HW + p0);
        float4 vp = pp[q];
        float4 vd = pd[q];
        float4 vn = pn[q];
        float4 so = make_float4(vd.x + vp.x, vd.y + vp.y, vd.z + vp.z, vd.w + vp.w);
        ((float4*)(outb + (size_t)(CC + j) * HW + p0))[q] = so;
        vs.x += vn.x; vs.y += vn.y; vs.z += vn.z; vs.w += vn.w;
    }
    *(float4*)&snegA[cgrp * PIX + q * 4] = vs;
    __syncthreads();

    // ---- neg mean (first wave), out row CC+HALF, mean to LDS ----
    if (tid < 64) {
        float m = 0.f;
        #pragma unroll
        for (int k = 0; k < 16; k++) m += snegA[k * PIX + tid];
        m *= (1.0f / HALF);
        mlds[tid] = m;
        outb[(size_t)(CC + HALF) * HW + p0 + tid] = x1b[(size_t)HALF * HW + p0 + tid] + m;
    }
    __syncthreads();

    // ---- phase B: z[32] accumulate, gather from global (cache-hot) ----
    int sg = __builtin_amdgcn_readfirstlane(w);
    const float* wbase = WT + sg * 32;
    int p = p0 + lane;
    float z[32];
    #pragma unroll
    for (int k = 0; k < 32; k++) z[k] = 0.f;
    #pragma unroll 4
    for (int i = 0; i < HALF; i++) {
        int c = pidx[i];                       // uniform -> s_load
        float v = x1b[(size_t)c * HW + p];     // 256B coalesced per wave
        const float* wc = wbase + i * 128;     // uniform -> s_load
        #pragma unroll
        for (int k = 0; k < 32; k++) z[k] += wc[k] * v;
    }
    {   // mean contribution (input row 128)
        float v = mlds[lane];
        const float* wc = wbase + HALF * 128;
        #pragma unroll
        for (int k = 0; k < 32; k++) z[k] += wc[k] * v;
    }

    // ---- epilogue: BN + leaky + residual for o = sg*32 + k ----
    #pragma unroll
    for (int k = 0; k < 32; k++) {
        int o = sg * 32 + k;
        if (o < OCH) {
            float scale = bn_gamma[o] * rsqrtf(bn_var[o] + BN_EPS);
            float zz = (z[k] - bn_mean[o]) * scale + bn_beta[o];
            float t2 = zz > 0.f ? zz : 0.1f * zz;
            outb[(size_t)(CC + HALF + 1 + o) * HW + p] =
                x1b[(size_t)(HALF + 1 + o) * HW + p] + t2;
        }
    }

    // ---- phase D: x0 copy, float4 ----
    #pragma unroll 4
    for (int s = 0; s < 16; s++) {
        int c = s * 16 + cgrp;
        float4 v = ((const float4*)(x0b + (size_t)c * HW + p0))[q];
        ((float4*)(outb + (size_t)c * HW + p0))[q] = v;
    }
}

extern "C" void kernel_launch(void* const* d_in, const int* in_sizes, int n_in,
                              void* d_out, int out_size, void* d_ws, size_t ws_size,
                              hipStream_t stream) {
    const float* x0      = (const float*)d_in[0];
    const float* x1      = (const float*)d_in[1];
    const float* eca_w   = (const float*)d_in[2];
    const float* conv_w  = (const float*)d_in[3];
    const float* bn_gamma= (const float*)d_in[4];
    const float* bn_beta = (const float*)d_in[5];
    const float* bn_mean = (const float*)d_in[6];
    const float* bn_var  = (const float*)d_in[7];
    float* out = (float*)d_out;

    float* ws    = (float*)d_ws;
    float* means = ws;                       // 4096 f32
    int*   posidx = (int*)(ws + 4096);       // 2048 i32
    int*   negidx = posidx + 2048;           // 2048 i32
    float* WT    = ws + 4096 + 2048 + 2048;  // 129*128 f32

    k_means<<<BB * CC, 256, 0, stream>>>(x1, means);
    k_select<<<BB, 256, 0, stream>>>(means, eca_w, posidx, negidx);
    k_wt<<<65, 256, 0, stream>>>(conv_w, WT);
    k_main<<<BB * (HW / PIX), 256, 0, stream>>>(x0, x1, WT, posidx, negidx,
                                                bn_gamma, bn_beta, bn_mean, bn_var, out);
}